// Round 4
// baseline (629.936 us; speedup 1.0000x reference)
//
#include <hip/hip_runtime.h>

// SSIM loss — round 4: fused register-sliding-window version.
// R3 evidence: dur 78us, occupancy 25% (LDS 41.5KB -> 3 blocks/CU), VALUBusy 37%,
// HBM 15% -> latency/occupancy-bound. Fix: eliminate hs* LDS buffers (26.9KB) by
// fusing h+v box sums into per-thread register sliding windows; Y stored as
// interleaved float2 (ds_read_b64). LDS 41.5KB -> 14.2KB, one barrier instead of two.

#define IMG    512
#define SHAVE  10
#define OUTW   492            // 512 - 2*SHAVE
#define TILE   32
#define HALO   5
#define REG    (TILE + 2*HALO)   // 42
#define NTILES 16             // ceil(492/32)
#define NBATCH 16
#define NBLOCKS (NTILES*NTILES*NBATCH)  // 4096

__device__ __forceinline__ float ssim_term(float s, float h, float ss, float hh, float sh)
{
    const float C1 = 6.5025f;     // (0.01*255)^2
    const float C2 = 58.5225f;    // (0.03*255)^2
    const float inv121 = 1.0f / 121.0f;
    const float mu1   = s * inv121;
    const float mu2   = h * inv121;
    const float mu1sq = mu1 * mu1;
    const float mu2sq = mu2 * mu2;
    const float mu12  = mu1 * mu2;
    const float sig1  = ss * inv121 - mu1sq;
    const float sig2  = hh * inv121 - mu2sq;
    const float sig12 = sh * inv121 - mu12;
    const float num = (2.0f * mu12 + C1) * (2.0f * sig12 + C2);
    const float den = (mu1sq + mu2sq + C1) * (sig1 + sig2 + C2);
    return 1.0f - num / den;
}

__global__ __launch_bounds__(256, 4)
void ssim_tile_kernel(const float* __restrict__ sr,
                      const float* __restrict__ hr,
                      double* __restrict__ partials)
{
    __shared__ float2 y2[REG][REG];   // (Ysr, Yhr) interleaved, zero padded
    __shared__ double wsum[4];

    const int b   = blockIdx.z;
    const int oy0 = blockIdx.y * TILE;
    const int ox0 = blockIdx.x * TILE;
    const int tid = threadIdx.x;
    const int bid = blockIdx.x + NTILES * (blockIdx.y + NTILES * blockIdx.z);

    const float inv255 = 1.0f / 255.0f;
    const float w0 = 65.738f  / 256.0f;
    const float w1 = 129.057f / 256.0f;
    const float w2 = 25.064f  / 256.0f;

    const size_t cstride = (size_t)IMG * IMG;
    const size_t base    = (size_t)b * 3 * cstride;

    // ---- stage 1: global -> LDS, fused clip + RGB->Y, zero pad ----
    for (int i = tid; i < REG * REG; i += 256) {
        const int r  = i / REG;
        const int c  = i - r * REG;
        const int sy = oy0 - HALO + r;   // shaved coords
        const int sx = ox0 - HALO + c;
        float vs = 0.0f, vh = 0.0f;
        if (sy >= 0 && sy < OUTW && sx >= 0 && sx < OUTW) {
            const size_t idx = base + (size_t)(sy + SHAVE) * IMG + (sx + SHAVE);
            float s0 = fminf(fmaxf(sr[idx]               * inv255, 0.0f), 1.0f);
            float s1 = fminf(fmaxf(sr[idx +     cstride] * inv255, 0.0f), 1.0f);
            float s2 = fminf(fmaxf(sr[idx + 2 * cstride] * inv255, 0.0f), 1.0f);
            float h0 = fminf(fmaxf(hr[idx]               * inv255, 0.0f), 1.0f);
            float h1 = fminf(fmaxf(hr[idx +     cstride] * inv255, 0.0f), 1.0f);
            float h2 = fminf(fmaxf(hr[idx + 2 * cstride] * inv255, 0.0f), 1.0f);
            vs = w0 * s0 + w1 * s1 + w2 * s2;
            vh = w0 * h0 + w1 * h1 + w2 * h2;
        }
        y2[r][c] = make_float2(vs, vh);
    }
    __syncthreads();

    // ---- stage 2: fused horizontal + vertical sliding window, all in regs ----
    // thread t: output column oxl = t&31, 4-row run starting at local row grp*4.
    const int oxl = tid & 31;
    const int grp = tid >> 5;         // 0..7
    const int u0  = grp * 4;          // top ys-row of first 11-row window
    const int ox  = ox0 + oxl;

    float rS = 0.f, rH = 0.f, rSS = 0.f, rHH = 0.f, rSH = 0.f;   // running v-sums
    float tS[3], tH[3], tSS[3], tHH[3], tSH[3];                  // retained rows

    double local = 0.0;

#pragma unroll
    for (int u = 0; u < 11; ++u) {
        float s = 0.f, h = 0.f, ss = 0.f, hh = 0.f, sh = 0.f;
#pragma unroll
        for (int j = 0; j < 11; ++j) {
            const float2 v = y2[u0 + u][oxl + j];
            s  += v.x;       h  += v.y;
            ss += v.x * v.x; hh += v.y * v.y; sh += v.x * v.y;
        }
        rS += s; rH += h; rSS += ss; rHH += hh; rSH += sh;
        if (u < 3) { tS[u] = s; tH[u] = h; tSS[u] = ss; tHH[u] = hh; tSH[u] = sh; }
    }
    if (ox < OUTW && (oy0 + u0) < OUTW)
        local += (double)ssim_term(rS, rH, rSS, rHH, rSH);

#pragma unroll
    for (int k = 1; k <= 3; ++k) {
        float s = 0.f, h = 0.f, ss = 0.f, hh = 0.f, sh = 0.f;
#pragma unroll
        for (int j = 0; j < 11; ++j) {
            const float2 v = y2[u0 + 10 + k][oxl + j];
            s  += v.x;       h  += v.y;
            ss += v.x * v.x; hh += v.y * v.y; sh += v.x * v.y;
        }
        rS  += s  - tS [k - 1];
        rH  += h  - tH [k - 1];
        rSS += ss - tSS[k - 1];
        rHH += hh - tHH[k - 1];
        rSH += sh - tSH[k - 1];
        if (ox < OUTW && (oy0 + u0 + k) < OUTW)
            local += (double)ssim_term(rS, rH, rSS, rHH, rSH);
    }

    // ---- block reduction: wave shfl (64) -> LDS -> per-block partial ----
#pragma unroll
    for (int off = 32; off > 0; off >>= 1)
        local += __shfl_down(local, off, 64);
    const int lane = tid & 63;
    const int wv   = tid >> 6;
    if (lane == 0) wsum[wv] = local;
    __syncthreads();
    if (tid == 0)
        partials[bid] = wsum[0] + wsum[1] + wsum[2] + wsum[3];
}

__global__ __launch_bounds__(256)
void ssim_finalize(const double* __restrict__ partials,
                   float* __restrict__ out)
{
    __shared__ double wsum[4];
    const int tid = threadIdx.x;
    double local = 0.0;
#pragma unroll
    for (int i = 0; i < NBLOCKS / 256; ++i)
        local += partials[tid + 256 * i];
#pragma unroll
    for (int off = 32; off > 0; off >>= 1)
        local += __shfl_down(local, off, 64);
    const int lane = tid & 63;
    const int wv   = tid >> 6;
    if (lane == 0) wsum[wv] = local;
    __syncthreads();
    if (tid == 0)
        out[0] = (float)((wsum[0] + wsum[1] + wsum[2] + wsum[3]) / (double)NBATCH);
}

extern "C" void kernel_launch(void* const* d_in, const int* in_sizes, int n_in,
                              void* d_out, int out_size, void* d_ws, size_t ws_size,
                              hipStream_t stream)
{
    const float* sr = (const float*)d_in[0];
    const float* hr = (const float*)d_in[1];
    double* partials = (double*)d_ws;          // 4096 doubles = 32 KB
    float* out = (float*)d_out;

    // partials are written unconditionally by every block -> no memset needed.
    dim3 grid(NTILES, NTILES, NBATCH);
    ssim_tile_kernel<<<grid, 256, 0, stream>>>(sr, hr, partials);
    ssim_finalize<<<1, 256, 0, stream>>>(partials, out);
}

// Round 6
// 144.871 us; speedup vs baseline: 4.3483x; 4.3483x over previous
//
#include <hip/hip_runtime.h>

// SSIM loss — round 6 (R5 resubmit: R5 never ran, GPU broker timeout).
// R4 post-mortem: __launch_bounds__(256,4) + per-thread retained arrays ->
// VGPR cap 64 -> 1.2GB scratch spill traffic (WRITE_SIZE), dur 573us.
// R5/R6: back to R3's shared-LDS 3-stage structure, with work reduction:
//   stage2: products computed once per pixel + horizontal register sliding
//           (168 threads x 8-hsum runs), scalar named accumulators only.
//   stage3: stats packed float4 (+1-padded stride, conflict-free) + SH plane;
//           vertical register sliding, 4 outputs/thread.
//   No launch_bounds min-waves cap. Deterministic per-block partials.
// LDS: y2 14112 + hs4 22176 + hsSH 5544 + wsum 32 = 41.9KB (3 blocks/CU).

#define IMG    512
#define SHAVE  10
#define OUTW   492            // 512 - 2*SHAVE
#define TILE   32
#define HALO   5
#define REG    (TILE + 2*HALO)   // 42
#define NTILES 16             // ceil(492/32)
#define NBATCH 16
#define NBLOCKS (NTILES*NTILES*NBATCH)  // 4096

__device__ __forceinline__ float ssim_term(float s, float h, float ss, float hh, float sh)
{
    const float C1 = 6.5025f;     // (0.01*255)^2
    const float C2 = 58.5225f;    // (0.03*255)^2
    const float inv121 = 1.0f / 121.0f;
    const float mu1   = s * inv121;
    const float mu2   = h * inv121;
    const float mu1sq = mu1 * mu1;
    const float mu2sq = mu2 * mu2;
    const float mu12  = mu1 * mu2;
    const float sig1  = ss * inv121 - mu1sq;
    const float sig2  = hh * inv121 - mu2sq;
    const float sig12 = sh * inv121 - mu12;
    const float num = (2.0f * mu12 + C1) * (2.0f * sig12 + C2);
    const float den = (mu1sq + mu2sq + C1) * (sig1 + sig2 + C2);
    return 1.0f - num / den;
}

__global__ __launch_bounds__(256)
void ssim_tile_kernel(const float* __restrict__ sr,
                      const float* __restrict__ hr,
                      double* __restrict__ partials)
{
    __shared__ float2 y2[REG][REG];          // (Ysr,Yhr), zero padded
    __shared__ float4 hs4[REG][TILE + 1];    // h-sums (S,H,SS,HH), padded stride
    __shared__ float  hsSH[REG][TILE + 1];   // h-sums (SH), padded stride
    __shared__ double wsum[4];

    const int b   = blockIdx.z;
    const int oy0 = blockIdx.y * TILE;
    const int ox0 = blockIdx.x * TILE;
    const int tid = threadIdx.x;
    const int bid = blockIdx.x + NTILES * (blockIdx.y + NTILES * blockIdx.z);

    const float inv255 = 1.0f / 255.0f;
    const float w0 = 65.738f  / 256.0f;
    const float w1 = 129.057f / 256.0f;
    const float w2 = 25.064f  / 256.0f;

    const size_t cstride = (size_t)IMG * IMG;
    const size_t base    = (size_t)b * 3 * cstride;

    // ---- stage 1: global -> LDS, fused clip + RGB->Y, zero pad ----
    for (int i = tid; i < REG * REG; i += 256) {
        const int r  = i / REG;
        const int c  = i - r * REG;
        const int sy = oy0 - HALO + r;   // shaved coords
        const int sx = ox0 - HALO + c;
        float vs = 0.0f, vh = 0.0f;
        if (sy >= 0 && sy < OUTW && sx >= 0 && sx < OUTW) {
            const size_t idx = base + (size_t)(sy + SHAVE) * IMG + (sx + SHAVE);
            float s0 = fminf(fmaxf(sr[idx]               * inv255, 0.0f), 1.0f);
            float s1 = fminf(fmaxf(sr[idx +     cstride] * inv255, 0.0f), 1.0f);
            float s2 = fminf(fmaxf(sr[idx + 2 * cstride] * inv255, 0.0f), 1.0f);
            float h0 = fminf(fmaxf(hr[idx]               * inv255, 0.0f), 1.0f);
            float h1 = fminf(fmaxf(hr[idx +     cstride] * inv255, 0.0f), 1.0f);
            float h2 = fminf(fmaxf(hr[idx + 2 * cstride] * inv255, 0.0f), 1.0f);
            vs = w0 * s0 + w1 * s1 + w2 * s2;
            vh = w0 * h0 + w1 * h1 + w2 * h2;
        }
        y2[r][c] = make_float2(vs, vh);
    }
    __syncthreads();

    // ---- stage 2: horizontal 11-sums, products once + register sliding ----
    // 168 active threads: row r = tid>>2 (0..41), run of 8 cols c0 = (tid&3)*8.
    if (tid < 4 * REG) {
        const int r  = tid >> 2;
        const int c0 = (tid & 3) * 8;
        float s = 0.f, h = 0.f, ss = 0.f, hh = 0.f, sh = 0.f;
#pragma unroll
        for (int j = 0; j < 11; ++j) {
            const float2 v = y2[r][c0 + j];
            s  += v.x;                 h  += v.y;
            ss = fmaf(v.x, v.x, ss);   hh = fmaf(v.y, v.y, hh);
            sh = fmaf(v.x, v.y, sh);
        }
        hs4[r][c0]  = make_float4(s, h, ss, hh);
        hsSH[r][c0] = sh;
#pragma unroll
        for (int k = 1; k < 8; ++k) {
            const float2 a = y2[r][c0 + 10 + k];   // incoming column
            const float2 d = y2[r][c0 + k - 1];    // outgoing column
            s  += a.x - d.x;
            h  += a.y - d.y;
            ss += a.x * a.x - d.x * d.x;
            hh += a.y * a.y - d.y * d.y;
            sh += a.x * a.y - d.x * d.y;
            hs4[r][c0 + k]  = make_float4(s, h, ss, hh);
            hsSH[r][c0 + k] = sh;
        }
    }
    __syncthreads();

    // ---- stage 3: vertical 11-sums via register sliding + SSIM ----
    // thread: output column oxl = tid&31, 4-row run starting at (tid>>5)*4.
    const int oxl = tid & 31;
    const int u0  = (tid >> 5) * 4;      // 0,4,...,28 ; windows use rows u0..u0+13
    const int ox  = ox0 + oxl;

    float s = 0.f, h = 0.f, ss = 0.f, hh = 0.f, sh = 0.f;
#pragma unroll
    for (int u = 0; u < 11; ++u) {
        const float4 q = hs4[u0 + u][oxl];
        s += q.x; h += q.y; ss += q.z; hh += q.w;
        sh += hsSH[u0 + u][oxl];
    }
    double local = 0.0;
    if (ox < OUTW && (oy0 + u0) < OUTW)
        local += (double)ssim_term(s, h, ss, hh, sh);
#pragma unroll
    for (int k = 1; k <= 3; ++k) {
        const float4 qa = hs4[u0 + 10 + k][oxl];   // incoming row
        const float4 qd = hs4[u0 + k - 1][oxl];    // outgoing row
        s  += qa.x - qd.x;
        h  += qa.y - qd.y;
        ss += qa.z - qd.z;
        hh += qa.w - qd.w;
        sh += hsSH[u0 + 10 + k][oxl] - hsSH[u0 + k - 1][oxl];
        if (ox < OUTW && (oy0 + u0 + k) < OUTW)
            local += (double)ssim_term(s, h, ss, hh, sh);
    }

    // ---- block reduction: wave shfl (64) -> LDS -> per-block partial ----
#pragma unroll
    for (int off = 32; off > 0; off >>= 1)
        local += __shfl_down(local, off, 64);
    const int lane = tid & 63;
    const int wv   = tid >> 6;
    if (lane == 0) wsum[wv] = local;
    __syncthreads();
    if (tid == 0)
        partials[bid] = wsum[0] + wsum[1] + wsum[2] + wsum[3];
}

__global__ __launch_bounds__(256)
void ssim_finalize(const double* __restrict__ partials,
                   float* __restrict__ out)
{
    __shared__ double wsum[4];
    const int tid = threadIdx.x;
    double local = 0.0;
#pragma unroll
    for (int i = 0; i < NBLOCKS / 256; ++i)
        local += partials[tid + 256 * i];
#pragma unroll
    for (int off = 32; off > 0; off >>= 1)
        local += __shfl_down(local, off, 64);
    const int lane = tid & 63;
    const int wv   = tid >> 6;
    if (lane == 0) wsum[wv] = local;
    __syncthreads();
    if (tid == 0)
        out[0] = (float)((wsum[0] + wsum[1] + wsum[2] + wsum[3]) / (double)NBATCH);
}

extern "C" void kernel_launch(void* const* d_in, const int* in_sizes, int n_in,
                              void* d_out, int out_size, void* d_ws, size_t ws_size,
                              hipStream_t stream)
{
    const float* sr = (const float*)d_in[0];
    const float* hr = (const float*)d_in[1];
    double* partials = (double*)d_ws;          // 4096 doubles = 32 KB
    float* out = (float*)d_out;

    // partials are written unconditionally by every block -> no memset needed.
    dim3 grid(NTILES, NTILES, NBATCH);
    ssim_tile_kernel<<<grid, 256, 0, stream>>>(sr, hr, partials);
    ssim_finalize<<<1, 256, 0, stream>>>(partials, out);
}

// Round 7
// 138.905 us; speedup vs baseline: 4.5350x; 1.0429x over previous
//
#include <hip/hip_runtime.h>

// SSIM loss — round 7.
// R6 evidence: tile 54us, VALU 27%, HBM 23%, occupancy 27% (41.9KB LDS -> 3
// blocks/CU) -> latency-bound. Fix: 32x16 output tile -> LDS 25.3KB -> 6
// blocks/CU (75% occupancy cap). Structure otherwise identical to R6:
//   stage1: global->LDS fused clip+RGB->Y (float2, zero-padded)
//   stage2: horizontal 11-sums, products once + register sliding (208 thr x 4)
//   stage3: vertical 11-sums, register sliding, 2 outputs/thread
//   deterministic per-block partials, separate tiny finalize kernel.

#define IMG    512
#define SHAVE  10
#define OUTW   492            // 512 - 2*SHAVE
#define TW     32             // tile width  (x)
#define TH     16             // tile height (y)
#define HALO   5
#define REGW   (TW + 2*HALO)  // 42
#define REGH   (TH + 2*HALO)  // 26
#define NTX    16             // ceil(492/32)
#define NTY    31             // ceil(492/16)
#define NBATCH 16
#define NBLOCKS (NTX*NTY*NBATCH)   // 7936 = 256*31

__device__ __forceinline__ float ssim_term(float s, float h, float ss, float hh, float sh)
{
    const float C1 = 6.5025f;     // (0.01*255)^2
    const float C2 = 58.5225f;    // (0.03*255)^2
    const float inv121 = 1.0f / 121.0f;
    const float mu1   = s * inv121;
    const float mu2   = h * inv121;
    const float mu1sq = mu1 * mu1;
    const float mu2sq = mu2 * mu2;
    const float mu12  = mu1 * mu2;
    const float sig1  = ss * inv121 - mu1sq;
    const float sig2  = hh * inv121 - mu2sq;
    const float sig12 = sh * inv121 - mu12;
    const float num = (2.0f * mu12 + C1) * (2.0f * sig12 + C2);
    const float den = (mu1sq + mu2sq + C1) * (sig1 + sig2 + C2);
    return 1.0f - num / den;
}

__global__ __launch_bounds__(256)
void ssim_tile_kernel(const float* __restrict__ sr,
                      const float* __restrict__ hr,
                      double* __restrict__ partials)
{
    __shared__ float2 y2[REGH][REGW];        // (Ysr,Yhr), zero padded   8736 B
    __shared__ float4 hs4[REGH][TW + 1];     // h-sums (S,H,SS,HH)      13728 B
    __shared__ float  hsSH[REGH][TW + 1];    // h-sums (SH)              3432 B
    __shared__ double wsum[4];

    const int b   = blockIdx.z;
    const int oy0 = blockIdx.y * TH;
    const int ox0 = blockIdx.x * TW;
    const int tid = threadIdx.x;
    const int bid = blockIdx.x + NTX * (blockIdx.y + NTY * blockIdx.z);

    const float inv255 = 1.0f / 255.0f;
    const float w0 = 65.738f  / 256.0f;
    const float w1 = 129.057f / 256.0f;
    const float w2 = 25.064f  / 256.0f;

    const size_t cstride = (size_t)IMG * IMG;
    const size_t base    = (size_t)b * 3 * cstride;

    // ---- stage 1: global -> LDS, fused clip + RGB->Y, zero pad ----
    for (int i = tid; i < REGH * REGW; i += 256) {
        const int r  = i / REGW;
        const int c  = i - r * REGW;
        const int sy = oy0 - HALO + r;   // shaved coords
        const int sx = ox0 - HALO + c;
        float vs = 0.0f, vh = 0.0f;
        if (sy >= 0 && sy < OUTW && sx >= 0 && sx < OUTW) {
            const size_t idx = base + (size_t)(sy + SHAVE) * IMG + (sx + SHAVE);
            float s0 = fminf(fmaxf(sr[idx]               * inv255, 0.0f), 1.0f);
            float s1 = fminf(fmaxf(sr[idx +     cstride] * inv255, 0.0f), 1.0f);
            float s2 = fminf(fmaxf(sr[idx + 2 * cstride] * inv255, 0.0f), 1.0f);
            float h0 = fminf(fmaxf(hr[idx]               * inv255, 0.0f), 1.0f);
            float h1 = fminf(fmaxf(hr[idx +     cstride] * inv255, 0.0f), 1.0f);
            float h2 = fminf(fmaxf(hr[idx + 2 * cstride] * inv255, 0.0f), 1.0f);
            vs = w0 * s0 + w1 * s1 + w2 * s2;
            vh = w0 * h0 + w1 * h1 + w2 * h2;
        }
        y2[r][c] = make_float2(vs, vh);
    }
    __syncthreads();

    // ---- stage 2: horizontal 11-sums, products once + register sliding ----
    // 208 active threads: row r = tid>>3 (0..25), run of 4 cols c0 = (tid&7)*4.
    if (tid < 8 * REGH) {
        const int r  = tid >> 3;
        const int c0 = (tid & 7) * 4;
        float s = 0.f, h = 0.f, ss = 0.f, hh = 0.f, sh = 0.f;
#pragma unroll
        for (int j = 0; j < 11; ++j) {
            const float2 v = y2[r][c0 + j];
            s  += v.x;                 h  += v.y;
            ss = fmaf(v.x, v.x, ss);   hh = fmaf(v.y, v.y, hh);
            sh = fmaf(v.x, v.y, sh);
        }
        hs4[r][c0]  = make_float4(s, h, ss, hh);
        hsSH[r][c0] = sh;
#pragma unroll
        for (int k = 1; k < 4; ++k) {
            const float2 a = y2[r][c0 + 10 + k];   // incoming column
            const float2 d = y2[r][c0 + k - 1];    // outgoing column
            s  += a.x - d.x;
            h  += a.y - d.y;
            ss += a.x * a.x - d.x * d.x;
            hh += a.y * a.y - d.y * d.y;
            sh += a.x * a.y - d.x * d.y;
            hs4[r][c0 + k]  = make_float4(s, h, ss, hh);
            hsSH[r][c0 + k] = sh;
        }
    }
    __syncthreads();

    // ---- stage 3: vertical 11-sums via register sliding + SSIM ----
    // thread: output column oxl = tid&31, 2-row run starting at (tid>>5)*2.
    const int oxl = tid & 31;
    const int r0  = (tid >> 5) * 2;      // 0,2,...,14 ; windows use rows r0..r0+11
    const int ox  = ox0 + oxl;

    float s = 0.f, h = 0.f, ss = 0.f, hh = 0.f, sh = 0.f;
#pragma unroll
    for (int u = 0; u < 11; ++u) {
        const float4 q = hs4[r0 + u][oxl];
        s += q.x; h += q.y; ss += q.z; hh += q.w;
        sh += hsSH[r0 + u][oxl];
    }
    double local = 0.0;
    if (ox < OUTW && (oy0 + r0) < OUTW)
        local += (double)ssim_term(s, h, ss, hh, sh);
    {
        const float4 qa = hs4[r0 + 11][oxl];   // incoming row
        const float4 qd = hs4[r0][oxl];        // outgoing row
        s  += qa.x - qd.x;
        h  += qa.y - qd.y;
        ss += qa.z - qd.z;
        hh += qa.w - qd.w;
        sh += hsSH[r0 + 11][oxl] - hsSH[r0][oxl];
        if (ox < OUTW && (oy0 + r0 + 1) < OUTW)
            local += (double)ssim_term(s, h, ss, hh, sh);
    }

    // ---- block reduction: wave shfl (64) -> LDS -> per-block partial ----
#pragma unroll
    for (int off = 32; off > 0; off >>= 1)
        local += __shfl_down(local, off, 64);
    const int lane = tid & 63;
    const int wv   = tid >> 6;
    if (lane == 0) wsum[wv] = local;
    __syncthreads();
    if (tid == 0)
        partials[bid] = wsum[0] + wsum[1] + wsum[2] + wsum[3];
}

__global__ __launch_bounds__(256)
void ssim_finalize(const double* __restrict__ partials,
                   float* __restrict__ out)
{
    __shared__ double wsum[4];
    const int tid = threadIdx.x;
    double local = 0.0;
#pragma unroll
    for (int i = 0; i < NBLOCKS / 256; ++i)     // 7936 = 256*31
        local += partials[tid + 256 * i];
#pragma unroll
    for (int off = 32; off > 0; off >>= 1)
        local += __shfl_down(local, off, 64);
    const int lane = tid & 63;
    const int wv   = tid >> 6;
    if (lane == 0) wsum[wv] = local;
    __syncthreads();
    if (tid == 0)
        out[0] = (float)((wsum[0] + wsum[1] + wsum[2] + wsum[3]) / (double)NBATCH);
}

extern "C" void kernel_launch(void* const* d_in, const int* in_sizes, int n_in,
                              void* d_out, int out_size, void* d_ws, size_t ws_size,
                              hipStream_t stream)
{
    const float* sr = (const float*)d_in[0];
    const float* hr = (const float*)d_in[1];
    double* partials = (double*)d_ws;          // 7936 doubles = 62 KB
    float* out = (float*)d_out;

    // partials are written unconditionally by every block -> no memset needed.
    dim3 grid(NTX, NTY, NBATCH);
    ssim_tile_kernel<<<grid, 256, 0, stream>>>(sr, hr, partials);
    ssim_finalize<<<1, 256, 0, stream>>>(partials, out);
}